// Round 1
// baseline (330.813 us; speedup 1.0000x reference)
//
#include <hip/hip_runtime.h>

#define NB    131072   // batch rows
#define TPB   256      // threads per block = rows per block
#define FANIN 260
#define PADF4 9        // LDS row stride = 36 floats = 9 float4 (144 B, 16B-aligned, conflict-free)

__device__ __forceinline__ float sigm_(float x) { return 1.0f / (1.0f + __expf(-x)); }
__device__ __forceinline__ float tanh_(float x) { return 1.0f - 2.0f / (__expf(2.0f * x) + 1.0f); }

// Single fused kernel: NO workspace use (avoids the 512 MiB ws re-poison fills
// that dominated the timed loop). Weights are repacked per-block into LDS
// (k-major wl[k][16], gw = g*4+w), bias+theta fused into bth[16].
__global__ __launch_bounds__(TPB, 2) void qlstm_fused(
        const float* __restrict__ x,  const float* __restrict__ hx,
        const float* __restrict__ cx,
        const float* __restrict__ Wf, const float* __restrict__ bf,
        const float* __restrict__ Wi, const float* __restrict__ bi,
        const float* __restrict__ Wu, const float* __restrict__ bu,
        const float* __restrict__ Wo, const float* __restrict__ bo,
        const float* __restrict__ thf, const float* __restrict__ thi,
        const float* __restrict__ thu, const float* __restrict__ tho,
        float* __restrict__ out) {
    __shared__ float xs[TPB * 36];       // 36864 B  x tile: 256 rows x 32 cols, stride 36
    __shared__ float wl[FANIN * 16];     // 16640 B  repacked weights, k-major
    __shared__ float bth[16];            // bias + theta
    // total 53568 B -> 2 blocks/CU (grid is 512 = 2/CU anyway)

    const int tid  = threadIdx.x;
    const int row0 = blockIdx.x * TPB;
    const int row  = row0 + tid;

    const float4* x4  = (const float4*)x;   // x is [NB][64 float4]
    float4*       xs4 = (float4*)xs;

    // Own-row hx/cx issued early; latency hidden under staging/compute.
    float4 hv  = ((const float4*)hx)[row];
    float4 cxv = ((const float4*)cx)[row];

    // ---- Prologue: prefetch stage 0 into regs, repack weights, write LDS ----
    float4 pf[8];
#pragma unroll
    for (int u = 0; u < 8; ++u) {
        int f = tid + (u << 8);
        pf[u] = x4[(size_t)(row0 + (f >> 3)) * 64 + (f & 7)];
    }

    for (int k = tid; k < FANIN; k += TPB) {
#pragma unroll
        for (int g = 0; g < 4; ++g) {
            const float* Wg = (g == 0) ? Wf : (g == 1) ? Wi : (g == 2) ? Wu : Wo;
#pragma unroll
            for (int w = 0; w < 4; ++w)
                wl[k * 16 + g * 4 + w] = Wg[w * FANIN + k];
        }
    }
    if (tid < 16) {
        int g = tid >> 2, w = tid & 3;
        const float* bg = (g == 0) ? bf  : (g == 1) ? bi  : (g == 2) ? bu  : bo;
        const float* tg = (g == 0) ? thf : (g == 1) ? thi : (g == 2) ? thu : tho;
        bth[tid] = bg[w] + tg[w];
    }

#pragma unroll
    for (int u = 0; u < 8; ++u) {
        int f = tid + (u << 8);
        xs4[(f >> 3) * PADF4 + (f & 7)] = pf[u];
    }
    __syncthreads();

    float acc[16];
#pragma unroll
    for (int j = 0; j < 16; ++j) acc[j] = 0.0f;

    const float4* wl4 = (const float4*)wl;

    // ---- Main loop: T14 split — issue next-stage loads BEFORE compute ----
#pragma unroll
    for (int stage = 0; stage < 8; ++stage) {
        if (stage < 7) {
#pragma unroll
            for (int u = 0; u < 8; ++u) {
                int f = tid + (u << 8);
                // 8 consecutive lanes read one row's 128 B segment -> coalesced
                pf[u] = x4[(size_t)(row0 + (f >> 3)) * 64 + (stage + 1) * 8 + (f & 7)];
            }
        }
        // compute current stage: x via ds_read_b128 (own row), weights via
        // uniform-broadcast ds_read_b128 (compile-time offsets after unroll)
#pragma unroll
        for (int kk4 = 0; kk4 < 8; ++kk4) {
            float4 xv = xs4[tid * PADF4 + kk4];
#pragma unroll
            for (int m = 0; m < 4; ++m) {
                float xe = (m == 0) ? xv.x : (m == 1) ? xv.y : (m == 2) ? xv.z : xv.w;
                int k = stage * 32 + kk4 * 4 + m;
#pragma unroll
                for (int j4 = 0; j4 < 4; ++j4) {
                    float4 w = wl4[k * 4 + j4];
                    acc[j4 * 4 + 0] = fmaf(xe, w.x, acc[j4 * 4 + 0]);
                    acc[j4 * 4 + 1] = fmaf(xe, w.y, acc[j4 * 4 + 1]);
                    acc[j4 * 4 + 2] = fmaf(xe, w.z, acc[j4 * 4 + 2]);
                    acc[j4 * 4 + 3] = fmaf(xe, w.w, acc[j4 * 4 + 3]);
                }
            }
        }
        __syncthreads();   // everyone done READING xs (also drains pf vmcnt)
        if (stage < 7) {
#pragma unroll
            for (int u = 0; u < 8; ++u) {
                int f = tid + (u << 8);
                xs4[(f >> 3) * PADF4 + (f & 7)] = pf[u];
            }
            __syncthreads();  // writes visible before next compute
        }
    }

    // ---- Tail: k = 256..259 come from hx[row][0..3] ----
#pragma unroll
    for (int m = 0; m < 4; ++m) {
        float he = (m == 0) ? hv.x : (m == 1) ? hv.y : (m == 2) ? hv.z : hv.w;
        int k = 256 + m;
#pragma unroll
        for (int j4 = 0; j4 < 4; ++j4) {
            float4 w = wl4[k * 4 + j4];
            acc[j4 * 4 + 0] = fmaf(he, w.x, acc[j4 * 4 + 0]);
            acc[j4 * 4 + 1] = fmaf(he, w.y, acc[j4 * 4 + 1]);
            acc[j4 * 4 + 2] = fmaf(he, w.z, acc[j4 * 4 + 2]);
            acc[j4 * 4 + 3] = fmaf(he, w.w, acc[j4 * 4 + 3]);
        }
    }

    // ---- Quantum gate closed form ----
    // c_w = cos(angle_w + b_w + th_w); E0=c1*c2*c3, E1=c0*c1, E2=c0*c1*c2, E3=c0*c1*c2*c3
    float co[16];
#pragma unroll
    for (int j = 0; j < 16; ++j) co[j] = __cosf(acc[j] + bth[j]);

    float G[16];
#pragma unroll
    for (int g = 0; g < 4; ++g) {
        float c0 = co[g * 4 + 0], c1 = co[g * 4 + 1];
        float c2 = co[g * 4 + 2], c3 = co[g * 4 + 3];
        float e1 = c0 * c1;
        float e2 = e1 * c2;
        float e3 = e2 * c3;
        float e0 = c1 * c2 * c3;
        G[g * 4 + 0] = e0; G[g * 4 + 1] = e1; G[g * 4 + 2] = e2; G[g * 4 + 3] = e3;
    }

    float cxa[4] = {cxv.x, cxv.y, cxv.z, cxv.w};
    float hn[4], cn[4];
#pragma unroll
    for (int w = 0; w < 4; ++w) {
        float fg = sigm_(G[0 * 4 + w]);
        float ig = sigm_(G[1 * 4 + w]);
        float ug = tanh_(G[2 * 4 + w]);
        float og = sigm_(G[3 * 4 + w]);
        float c_ = fg * cxa[w] + ig * ug;
        cn[w] = c_;
        hn[w] = og * tanh_(c_);
    }

    ((float4*)out)[row]      = make_float4(hn[0], hn[1], hn[2], hn[3]);  // h_new
    ((float4*)out)[NB + row] = make_float4(cn[0], cn[1], cn[2], cn[3]);  // c_new
}

extern "C" void kernel_launch(void* const* d_in, const int* in_sizes, int n_in,
                              void* d_out, int out_size, void* d_ws, size_t ws_size,
                              hipStream_t stream) {
    const float* x   = (const float*)d_in[0];
    const float* hx  = (const float*)d_in[1];
    const float* cx  = (const float*)d_in[2];
    const float* Wf  = (const float*)d_in[3];
    const float* bf  = (const float*)d_in[4];
    const float* Wi  = (const float*)d_in[5];
    const float* bi  = (const float*)d_in[6];
    const float* Wu  = (const float*)d_in[7];
    const float* bu  = (const float*)d_in[8];
    const float* Wo  = (const float*)d_in[9];
    const float* bo  = (const float*)d_in[10];
    const float* thf = (const float*)d_in[11];
    const float* thi = (const float*)d_in[12];
    const float* thu = (const float*)d_in[13];
    const float* tho = (const float*)d_in[14];

    // NOTE: d_ws intentionally unused — keeping weights out of the workspace
    // removes the 512 MiB per-iteration ws re-poison fills from the timed path.
    (void)d_ws; (void)ws_size;

    qlstm_fused<<<NB / TPB, TPB, 0, stream>>>(
        x, hx, cx, Wf, bf, Wi, bi, Wu, bu, Wo, bo,
        thf, thi, thu, tho, (float*)d_out);
}

// Round 2
// 274.841 us; speedup vs baseline: 1.2037x; 1.2037x over previous
//
#include <hip/hip_runtime.h>

#define NB    131072   // batch rows
#define TPB   64       // ONE WAVE per block -> no __syncthreads coupling
#define FANIN 260
#define SROWF4 9       // LDS row stride: 9 float4 = 36 floats = 144 B

__device__ __forceinline__ float sigm_(float x) { return 1.0f / (1.0f + __expf(-x)); }
__device__ __forceinline__ float tanh_(float x) { return 1.0f - 2.0f / (__expf(2.0f * x) + 1.0f); }

// Repack the four [4,260] weight matrices into k-major Wp[k][16] (gw = g*4+w)
// and fuse bias+theta into bth[16]. Workspace re-poison is UNCONDITIONAL
// (measured r1: fills ran with ws unused), so using ws costs nothing.
__global__ void qlstm_prep(const float* __restrict__ Wf, const float* __restrict__ bf,
                           const float* __restrict__ Wi, const float* __restrict__ bi,
                           const float* __restrict__ Wu, const float* __restrict__ bu,
                           const float* __restrict__ Wo, const float* __restrict__ bo,
                           const float* __restrict__ thf, const float* __restrict__ thi,
                           const float* __restrict__ thu, const float* __restrict__ tho,
                           float* __restrict__ Wp, float* __restrict__ bth) {
    int t = blockIdx.x * blockDim.x + threadIdx.x;
    if (t < FANIN * 16) {
        int k = t >> 4, gw = t & 15, g = gw >> 2, w = gw & 3;
        const float* Wg = (g == 0) ? Wf : (g == 1) ? Wi : (g == 2) ? Wu : Wo;
        Wp[t] = Wg[w * FANIN + k];
    }
    if (t < 16) {
        int g = t >> 2, w = t & 3;
        const float* bg = (g == 0) ? bf  : (g == 1) ? bi  : (g == 2) ? bu  : bo;
        const float* tg = (g == 0) ? thf : (g == 1) ? thi : (g == 2) ? thu : tho;
        bth[t] = bg[w] + tg[w];
    }
}

__global__ __launch_bounds__(TPB) void qlstm_main(
        const float* __restrict__ x, const float* __restrict__ hx,
        const float* __restrict__ cx, const float* __restrict__ Wp,
        const float* __restrict__ bth, float* __restrict__ out) {
    // Double-buffered x tile: 2 x 64 rows x 36 floats = 18432 B -> 8 blocks/CU.
    // Stride 36 floats: ds_read/write_b128 hit all 32 banks at 8 accesses/bank
    // (the b128 minimum) -> conflict-free.
    __shared__ float4 xs4[2 * TPB * SROWF4];

    const int lane = threadIdx.x;
    const int row0 = blockIdx.x * TPB;
    const int row  = row0 + lane;

    const float4* x4 = (const float4*)x;  // x is [NB][64 float4]

    // Own-row hx/cx issued early; latency hides under the pipeline.
    float4 hv  = ((const float4*)hx)[row];
    float4 cxv = ((const float4*)cx)[row];

    // ---- Prologue: stage 0 into buffer 0 ----
    // f = lane + 64u -> r = f>>3, c4 = f&7: 8 consecutive lanes read one
    // row's 128 B segment -> full-sector coalescing.
    float4 pf[8];
#pragma unroll
    for (int u = 0; u < 8; ++u) {
        int f = lane + (u << 6);
        pf[u] = x4[(size_t)(row0 + (f >> 3)) * 64 + (f & 7)];
    }
#pragma unroll
    for (int u = 0; u < 8; ++u) {
        int f = lane + (u << 6);
        xs4[(f >> 3) * SROWF4 + (f & 7)] = pf[u];
    }

    float acc[16];
#pragma unroll
    for (int j = 0; j < 16; ++j) acc[j] = 0.0f;

    // ---- Main loop. unroll 2 (NOT full: full unroll let the scheduler hoist
    // all prefetch loads -> VGPR spill -> the 257 MB scratch writes of r1).
    // unroll 2 makes (stage&1) compile-time so buffer bases stay static.
#pragma unroll 2
    for (int stage = 0; stage < 8; ++stage) {
        float4* cur = &xs4[(stage & 1)        * (TPB * SROWF4)];
        float4* nxt = &xs4[((stage + 1) & 1)  * (TPB * SROWF4)];

        // T14: issue next stage's global loads BEFORE compute.
        if (stage < 7) {
#pragma unroll
            for (int u = 0; u < 8; ++u) {
                int f = lane + (u << 6);
                pf[u] = x4[(size_t)(row0 + (f >> 3)) * 64 + (stage + 1) * 8 + (f & 7)];
            }
        }

        // Own row from LDS (8 x ds_read_b128, conflict-free).
        float4 xr[8];
#pragma unroll
        for (int k4 = 0; k4 < 8; ++k4) xr[k4] = cur[lane * SROWF4 + k4];

        // Weights: wave-uniform address -> s_load (scalar pipe, no VMEM/LDS).
        const float* wbase = Wp + stage * 32 * 16;
#pragma unroll
        for (int k4 = 0; k4 < 8; ++k4) {
#pragma unroll
            for (int m = 0; m < 4; ++m) {
                float xe = (m == 0) ? xr[k4].x : (m == 1) ? xr[k4].y
                         : (m == 2) ? xr[k4].z : xr[k4].w;
                const float* wp = wbase + (k4 * 4 + m) * 16;
#pragma unroll
                for (int j = 0; j < 16; ++j) acc[j] = fmaf(xe, wp[j], acc[j]);
            }
        }

        // Write next stage into the other buffer. Single wave: DS ordering
        // within the wave makes this race-free without any barrier.
        if (stage < 7) {
#pragma unroll
            for (int u = 0; u < 8; ++u) {
                int f = lane + (u << 6);
                nxt[(f >> 3) * SROWF4 + (f & 7)] = pf[u];
            }
        }
    }

    // ---- Tail: k = 256..259 come from hx[row][0..3] ----
    {
        const float* wp = Wp + 256 * 16;
#pragma unroll
        for (int j = 0; j < 16; ++j) acc[j] = fmaf(hv.x, wp[j],      acc[j]);
#pragma unroll
        for (int j = 0; j < 16; ++j) acc[j] = fmaf(hv.y, wp[16 + j], acc[j]);
#pragma unroll
        for (int j = 0; j < 16; ++j) acc[j] = fmaf(hv.z, wp[32 + j], acc[j]);
#pragma unroll
        for (int j = 0; j < 16; ++j) acc[j] = fmaf(hv.w, wp[48 + j], acc[j]);
    }

    // ---- Quantum gate closed form ----
    // c_w = cos(angle_w + b_w + th_w); E0=c1*c2*c3, E1=c0*c1, E2=c0*c1*c2, E3=c0*c1*c2*c3
    float co[16];
#pragma unroll
    for (int j = 0; j < 16; ++j) co[j] = __cosf(acc[j] + bth[j]);

    float G[16];
#pragma unroll
    for (int g = 0; g < 4; ++g) {
        float c0 = co[g * 4 + 0], c1 = co[g * 4 + 1];
        float c2 = co[g * 4 + 2], c3 = co[g * 4 + 3];
        float e1 = c0 * c1;
        float e2 = e1 * c2;
        float e3 = e2 * c3;
        float e0 = c1 * c2 * c3;
        G[g * 4 + 0] = e0; G[g * 4 + 1] = e1; G[g * 4 + 2] = e2; G[g * 4 + 3] = e3;
    }

    float cxa[4] = {cxv.x, cxv.y, cxv.z, cxv.w};
    float hn[4], cn[4];
#pragma unroll
    for (int w = 0; w < 4; ++w) {
        float fg = sigm_(G[0 * 4 + w]);
        float ig = sigm_(G[1 * 4 + w]);
        float ug = tanh_(G[2 * 4 + w]);
        float og = sigm_(G[3 * 4 + w]);
        float c_ = fg * cxa[w] + ig * ug;
        cn[w] = c_;
        hn[w] = og * tanh_(c_);
    }

    ((float4*)out)[row]      = make_float4(hn[0], hn[1], hn[2], hn[3]);  // h_new
    ((float4*)out)[NB + row] = make_float4(cn[0], cn[1], cn[2], cn[3]);  // c_new
}

extern "C" void kernel_launch(void* const* d_in, const int* in_sizes, int n_in,
                              void* d_out, int out_size, void* d_ws, size_t ws_size,
                              hipStream_t stream) {
    const float* x   = (const float*)d_in[0];
    const float* hx  = (const float*)d_in[1];
    const float* cx  = (const float*)d_in[2];
    const float* Wf  = (const float*)d_in[3];
    const float* bf  = (const float*)d_in[4];
    const float* Wi  = (const float*)d_in[5];
    const float* bi  = (const float*)d_in[6];
    const float* Wu  = (const float*)d_in[7];
    const float* bu  = (const float*)d_in[8];
    const float* Wo  = (const float*)d_in[9];
    const float* bo  = (const float*)d_in[10];
    const float* thf = (const float*)d_in[11];
    const float* thi = (const float*)d_in[12];
    const float* thu = (const float*)d_in[13];
    const float* tho = (const float*)d_in[14];

    float* Wp  = (float*)d_ws;            // 260*16 floats = 16640 B
    float* bth = Wp + FANIN * 16;         // 16 floats

    qlstm_prep<<<(FANIN * 16 + 255) / 256, 256, 0, stream>>>(
        Wf, bf, Wi, bi, Wu, bu, Wo, bo, thf, thi, thu, tho, Wp, bth);

    qlstm_main<<<NB / TPB, TPB, 0, stream>>>(
        x, hx, cx, Wp, bth, (float*)d_out);
}

// Round 3
// 241.182 us; speedup vs baseline: 1.3716x; 1.1396x over previous
//
#include <hip/hip_runtime.h>

#define NB    131072   // batch rows
#define TPB   64       // one wave per block -> no barriers, per-wave pipeline
#define FANIN 260

__device__ __forceinline__ float sigm_(float x) { return 1.0f / (1.0f + __expf(-x)); }
__device__ __forceinline__ float tanh_(float x) { return 1.0f - 2.0f / (__expf(2.0f * x) + 1.0f); }

// Async global->LDS, 16 B per lane. Dest is wave-uniform base + lane*16 (HW rule,
// m104): swizzling must therefore be done on the per-lane GLOBAL address (m173).
__device__ __forceinline__ void gld_lds16(const float4* gsrc, float4* ldst) {
    __builtin_amdgcn_global_load_lds(
        (const __attribute__((address_space(1))) void*)gsrc,
        (__attribute__((address_space(3))) void*)ldst, 16, 0, 0);
}

// Repack the four [4,260] weight matrices into k-major Wp[k][16] (gw = g*4+w)
// and fuse bias+theta into bth[16]. ws re-poison is UNCONDITIONAL (measured r1),
// so using the workspace costs nothing.
__global__ void qlstm_prep(const float* __restrict__ Wf, const float* __restrict__ bf,
                           const float* __restrict__ Wi, const float* __restrict__ bi,
                           const float* __restrict__ Wu, const float* __restrict__ bu,
                           const float* __restrict__ Wo, const float* __restrict__ bo,
                           const float* __restrict__ thf, const float* __restrict__ thi,
                           const float* __restrict__ thu, const float* __restrict__ tho,
                           float* __restrict__ Wp, float* __restrict__ bth) {
    int t = blockIdx.x * blockDim.x + threadIdx.x;
    if (t < FANIN * 16) {
        int k = t >> 4, gw = t & 15, g = gw >> 2, w = gw & 3;
        const float* Wg = (g == 0) ? Wf : (g == 1) ? Wi : (g == 2) ? Wu : Wo;
        Wp[t] = Wg[w * FANIN + k];
    }
    if (t < 16) {
        int g = t >> 2, w = t & 3;
        const float* bg = (g == 0) ? bf  : (g == 1) ? bi  : (g == 2) ? bu  : bo;
        const float* tg = (g == 0) ? thf : (g == 1) ? thi : (g == 2) ? thu : tho;
        bth[t] = bg[w] + tg[w];
    }
}

__global__ __launch_bounds__(TPB, 2) void qlstm_main(
        const float* __restrict__ x, const float* __restrict__ hx,
        const float* __restrict__ cx, const float* __restrict__ Wp,
        const float* __restrict__ bth, float* __restrict__ out) {
    // Double-buffered x tile, LINEAR layout (required by global_load_lds),
    // XOR-swizzled via the global source: LDS slot f holds x element
    // (r = f>>3, c4 = (f&7) ^ (r&7)). 2 x 64 x 8 float4 = 16 KB -> ~10 blocks/CU.
    __shared__ float4 xs4[2 * TPB * 8];

    const int lane = threadIdx.x;
    const int row0 = blockIdx.x * TPB;
    const int row  = row0 + lane;
    const float4* x4 = (const float4*)x;  // x is [NB][64 float4]

    // Own-row hx/cx: issued first, drained by the stage-0 vmcnt(8) wait.
    float4 hv  = ((const float4*)hx)[row];
    float4 cxv = ((const float4*)cx)[row];

    // Per-lane swizzled global source for staging instruction u:
    // f = u*64 + lane -> r = u*8 + (lane>>3), c4 = (lane&7) ^ (lane>>3).
    // 8 consecutive lanes still cover one full 128 B row segment (permuted).
    const int rsub = lane >> 3;
    const int csw  = (lane & 7) ^ rsub;
    const size_t gbase = (size_t)(row0 + rsub) * 64 + csw;  // + u*8*64 + stage*8

    // ---- Prologue: stage 0 -> buffer 0 (async, zero VGPR round-trip) ----
#pragma unroll
    for (int u = 0; u < 8; ++u)
        gld_lds16(x4 + gbase + (size_t)u * 8 * 64, &xs4[u * 64]);

    float acc[16];
#pragma unroll
    for (int j = 0; j < 16; ++j) acc[j] = 0.0f;

#pragma unroll 2
    for (int stage = 0; stage < 8; ++stage) {
        const int cb = (stage & 1) * (TPB * 8);

        if (stage < 7) {
            // T14/T3: issue next stage's 8 async loads into the other buffer,
            // then counted wait: vmcnt(8) retires the CURRENT buffer's 8 loads
            // (+ hv/cxv at stage 0) while the 8 just issued stay in flight
            // across the whole FMA phase. Never vmcnt(0) mid-loop.
            const int nb_ = ((stage + 1) & 1) * (TPB * 8);
#pragma unroll
            for (int u = 0; u < 8; ++u)
                gld_lds16(x4 + gbase + (size_t)(stage + 1) * 8 + (size_t)u * 8 * 64,
                          &xs4[nb_ + u * 64]);
            asm volatile("s_waitcnt vmcnt(8)" ::: "memory");
        } else {
            asm volatile("s_waitcnt vmcnt(0)" ::: "memory");
        }

        // Weights: wave-uniform address -> scalar loads (s_load), no VMEM/LDS.
        const float* wbase = Wp + stage * 32 * 16;
#pragma unroll
        for (int k4 = 0; k4 < 8; ++k4) {
            // Read own row, column k4, through the XOR swizzle: per 8-lane
            // group the 8 b128 slots cover all 32 banks -> conflict-free.
            float4 xv = xs4[cb + lane * 8 + (k4 ^ (lane & 7))];
#pragma unroll
            for (int m = 0; m < 4; ++m) {
                float xe = (m == 0) ? xv.x : (m == 1) ? xv.y
                         : (m == 2) ? xv.z : xv.w;
                const float* wp = wbase + (k4 * 4 + m) * 16;
#pragma unroll
                for (int j = 0; j < 16; ++j) acc[j] = fmaf(xe, wp[j], acc[j]);
            }
        }
    }

    // ---- Tail: k = 256..259 come from hx[row][0..3] ----
    {
        const float* wp = Wp + 256 * 16;
#pragma unroll
        for (int j = 0; j < 16; ++j) acc[j] = fmaf(hv.x, wp[j],      acc[j]);
#pragma unroll
        for (int j = 0; j < 16; ++j) acc[j] = fmaf(hv.y, wp[16 + j], acc[j]);
#pragma unroll
        for (int j = 0; j < 16; ++j) acc[j] = fmaf(hv.z, wp[32 + j], acc[j]);
#pragma unroll
        for (int j = 0; j < 16; ++j) acc[j] = fmaf(hv.w, wp[48 + j], acc[j]);
    }

    // ---- Quantum gate closed form ----
    // c_w = cos(angle_w + b_w + th_w); E0=c1*c2*c3, E1=c0*c1, E2=c0*c1*c2, E3=c0*c1*c2*c3
    float co[16];
#pragma unroll
    for (int j = 0; j < 16; ++j) co[j] = __cosf(acc[j] + bth[j]);

    float G[16];
#pragma unroll
    for (int g = 0; g < 4; ++g) {
        float c0 = co[g * 4 + 0], c1 = co[g * 4 + 1];
        float c2 = co[g * 4 + 2], c3 = co[g * 4 + 3];
        float e1 = c0 * c1;
        float e2 = e1 * c2;
        float e3 = e2 * c3;
        float e0 = c1 * c2 * c3;
        G[g * 4 + 0] = e0; G[g * 4 + 1] = e1; G[g * 4 + 2] = e2; G[g * 4 + 3] = e3;
    }

    float cxa[4] = {cxv.x, cxv.y, cxv.z, cxv.w};
    float hn[4], cn[4];
#pragma unroll
    for (int w = 0; w < 4; ++w) {
        float fg = sigm_(G[0 * 4 + w]);
        float ig = sigm_(G[1 * 4 + w]);
        float ug = tanh_(G[2 * 4 + w]);
        float og = sigm_(G[3 * 4 + w]);
        float c_ = fg * cxa[w] + ig * ug;
        cn[w] = c_;
        hn[w] = og * tanh_(c_);
    }

    ((float4*)out)[row]      = make_float4(hn[0], hn[1], hn[2], hn[3]);  // h_new
    ((float4*)out)[NB + row] = make_float4(cn[0], cn[1], cn[2], cn[3]);  // c_new
}

extern "C" void kernel_launch(void* const* d_in, const int* in_sizes, int n_in,
                              void* d_out, int out_size, void* d_ws, size_t ws_size,
                              hipStream_t stream) {
    const float* x   = (const float*)d_in[0];
    const float* hx  = (const float*)d_in[1];
    const float* cx  = (const float*)d_in[2];
    const float* Wf  = (const float*)d_in[3];
    const float* bf  = (const float*)d_in[4];
    const float* Wi  = (const float*)d_in[5];
    const float* bi  = (const float*)d_in[6];
    const float* Wu  = (const float*)d_in[7];
    const float* bu  = (const float*)d_in[8];
    const float* Wo  = (const float*)d_in[9];
    const float* bo  = (const float*)d_in[10];
    const float* thf = (const float*)d_in[11];
    const float* thi = (const float*)d_in[12];
    const float* thu = (const float*)d_in[13];
    const float* tho = (const float*)d_in[14];

    float* Wp  = (float*)d_ws;            // 260*16 floats = 16640 B
    float* bth = Wp + FANIN * 16;         // 16 floats

    qlstm_prep<<<(FANIN * 16 + 255) / 256, 256, 0, stream>>>(
        Wf, bf, Wi, bi, Wu, bu, Wo, bo, thf, thi, thu, tho, Wp, bth);

    qlstm_main<<<NB / TPB, TPB, 0, stream>>>(
        x, hx, cx, Wp, bth, (float*)d_out);
}

// Round 4
// 228.245 us; speedup vs baseline: 1.4494x; 1.0567x over previous
//
#include <hip/hip_runtime.h>

#define NB    131072   // batch rows
#define TPB   128      // 2 waves/block: wave0 = k[0,128), wave1 = k[128,256) + hx tail
#define FANIN 260

__device__ __forceinline__ float sigm_(float x) { return 1.0f / (1.0f + __expf(-x)); }
__device__ __forceinline__ float tanh_(float x) { return 1.0f - 2.0f / (__expf(2.0f * x) + 1.0f); }

// Repack the four [4,260] weight matrices into k-major Wp[k][16] (gw = g*4+w)
// and fuse bias+theta into bth[16]. ws re-poison is UNCONDITIONAL (measured r1),
// so using the workspace costs nothing.
__global__ void qlstm_prep(const float* __restrict__ Wf, const float* __restrict__ bf,
                           const float* __restrict__ Wi, const float* __restrict__ bi,
                           const float* __restrict__ Wu, const float* __restrict__ bu,
                           const float* __restrict__ Wo, const float* __restrict__ bo,
                           const float* __restrict__ thf, const float* __restrict__ thi,
                           const float* __restrict__ thu, const float* __restrict__ tho,
                           float* __restrict__ Wp, float* __restrict__ bth) {
    int t = blockIdx.x * blockDim.x + threadIdx.x;
    if (t < FANIN * 16) {
        int k = t >> 4, gw = t & 15, g = gw >> 2, w = gw & 3;
        const float* Wg = (g == 0) ? Wf : (g == 1) ? Wi : (g == 2) ? Wu : Wo;
        Wp[t] = Wg[w * FANIN + k];
    }
    if (t < 16) {
        int g = t >> 2, w = t & 3;
        const float* bg = (g == 0) ? bf  : (g == 1) ? bi  : (g == 2) ? bu  : bo;
        const float* tg = (g == 0) ? thf : (g == 1) ? thi : (g == 2) ? thu : tho;
        bth[t] = bg[w] + tg[w];
    }
}

// One 32-column chunk: 128 FMAs per j, fully static indices -> stays in VGPRs.
__device__ __forceinline__ void consume8(const float4 (&b)[8],
                                         const float* __restrict__ wb,
                                         float (&acc)[16]) {
#pragma unroll
    for (int u = 0; u < 8; ++u) {
#pragma unroll
        for (int m = 0; m < 4; ++m) {
            float xe = (m == 0) ? b[u].x : (m == 1) ? b[u].y
                     : (m == 2) ? b[u].z : b[u].w;
            const float* wp = wb + (u * 4 + m) * 16;   // wave-uniform -> s_load
#pragma unroll
            for (int j = 0; j < 16; ++j) acc[j] = fmaf(xe, wp[j], acc[j]);
        }
    }
}

__global__ __launch_bounds__(TPB, 4) void qlstm_main(
        const float* __restrict__ x, const float* __restrict__ hx,
        const float* __restrict__ cx, const float* __restrict__ Wp,
        const float* __restrict__ bth, float* __restrict__ out) {
    __shared__ float accx[64 * 16];   // wave1's partial angles (4 KB)

    const int tid  = threadIdx.x;
    const int lane = tid & 63;
    const int wv   = tid >> 6;                             // wave id in block
    const int wvu  = __builtin_amdgcn_readfirstlane(wv);   // force SGPR (weight addr uniformity)
    const int row0 = blockIdx.x * 64;
    const int row  = row0 + lane;

    // This wave's half of x: 32 float4 per row. Per-stage chunk (8 float4)
    // is exactly one 128 B line per row -> the 8 sub-reads of a line are
    // consecutive -> L1/L2 serve 7/8 of requests; HBM traffic stays 1x.
    const float4* xr = (const float4*)x + (size_t)row * 64 + wvu * 32;
    const float*  wW = Wp + wvu * (4 * 512);               // this wave's 4 k-stages

    float4 hv = make_float4(0.f, 0.f, 0.f, 0.f);
    float4 cxv = make_float4(0.f, 0.f, 0.f, 0.f);
    if (wvu == 1) hv  = ((const float4*)hx)[row];
    else          cxv = ((const float4*)cx)[row];

    float acc[16];
#pragma unroll
    for (int j = 0; j < 16; ++j) acc[j] = 0.0f;

    // Register double buffer, manual 2-deep rotation. Plain register loads:
    // the compiler inserts PRECISE counted vmcnt before first use (unlike the
    // global_load_lds path), so stage s+1's loads stay in flight across
    // stage s's FMA phase with no inline asm and no barriers.
    float4 A[8], B[8];
#pragma unroll
    for (int u = 0; u < 8; ++u) A[u] = xr[u];          // stage 0
#pragma unroll
    for (int u = 0; u < 8; ++u) B[u] = xr[8 + u];      // stage 1
    consume8(A, wW + 0 * 512, acc);
#pragma unroll
    for (int u = 0; u < 8; ++u) A[u] = xr[16 + u];     // stage 2
    consume8(B, wW + 1 * 512, acc);
#pragma unroll
    for (int u = 0; u < 8; ++u) B[u] = xr[24 + u];     // stage 3
    consume8(A, wW + 2 * 512, acc);
    consume8(B, wW + 3 * 512, acc);

    if (wvu == 1) {
        // Tail: k = 256..259 come from hx[row][0..3].
        const float* wp = Wp + 256 * 16;
#pragma unroll
        for (int j = 0; j < 16; ++j) acc[j] = fmaf(hv.x, wp[j],      acc[j]);
#pragma unroll
        for (int j = 0; j < 16; ++j) acc[j] = fmaf(hv.y, wp[16 + j], acc[j]);
#pragma unroll
        for (int j = 0; j < 16; ++j) acc[j] = fmaf(hv.z, wp[32 + j], acc[j]);
#pragma unroll
        for (int j = 0; j < 16; ++j) acc[j] = fmaf(hv.w, wp[48 + j], acc[j]);
        // Publish partials (2-way bank aliasing on b128 writes = free).
#pragma unroll
        for (int j4 = 0; j4 < 4; ++j4)
            ((float4*)accx)[lane * 4 + j4] =
                make_float4(acc[j4 * 4 + 0], acc[j4 * 4 + 1],
                            acc[j4 * 4 + 2], acc[j4 * 4 + 3]);
    }
    __syncthreads();
    if (wvu == 0) {
#pragma unroll
        for (int j4 = 0; j4 < 4; ++j4) {
            float4 p = ((const float4*)accx)[lane * 4 + j4];
            acc[j4 * 4 + 0] += p.x;
            acc[j4 * 4 + 1] += p.y;
            acc[j4 * 4 + 2] += p.z;
            acc[j4 * 4 + 3] += p.w;
        }

        // ---- Quantum gate closed form ----
        // c_w = cos(angle_w + b_w + th_w); E0=c1*c2*c3, E1=c0*c1, E2=c0*c1*c2, E3=c0*c1*c2*c3
        float co[16];
#pragma unroll
        for (int j = 0; j < 16; ++j) co[j] = __cosf(acc[j] + bth[j]);

        float G[16];
#pragma unroll
        for (int g = 0; g < 4; ++g) {
            float c0 = co[g * 4 + 0], c1 = co[g * 4 + 1];
            float c2 = co[g * 4 + 2], c3 = co[g * 4 + 3];
            float e1 = c0 * c1;
            float e2 = e1 * c2;
            float e3 = e2 * c3;
            float e0 = c1 * c2 * c3;
            G[g * 4 + 0] = e0; G[g * 4 + 1] = e1; G[g * 4 + 2] = e2; G[g * 4 + 3] = e3;
        }

        float cxa[4] = {cxv.x, cxv.y, cxv.z, cxv.w};
        float hn[4], cn[4];
#pragma unroll
        for (int w = 0; w < 4; ++w) {
            float fg = sigm_(G[0 * 4 + w]);
            float ig = sigm_(G[1 * 4 + w]);
            float ug = tanh_(G[2 * 4 + w]);
            float og = sigm_(G[3 * 4 + w]);
            float c_ = fg * cxa[w] + ig * ug;
            cn[w] = c_;
            hn[w] = og * tanh_(c_);
        }

        ((float4*)out)[row]      = make_float4(hn[0], hn[1], hn[2], hn[3]);  // h_new
        ((float4*)out)[NB + row] = make_float4(cn[0], cn[1], cn[2], cn[3]);  // c_new
    }
}

extern "C" void kernel_launch(void* const* d_in, const int* in_sizes, int n_in,
                              void* d_out, int out_size, void* d_ws, size_t ws_size,
                              hipStream_t stream) {
    const float* x   = (const float*)d_in[0];
    const float* hx  = (const float*)d_in[1];
    const float* cx  = (const float*)d_in[2];
    const float* Wf  = (const float*)d_in[3];
    const float* bf  = (const float*)d_in[4];
    const float* Wi  = (const float*)d_in[5];
    const float* bi  = (const float*)d_in[6];
    const float* Wu  = (const float*)d_in[7];
    const float* bu  = (const float*)d_in[8];
    const float* Wo  = (const float*)d_in[9];
    const float* bo  = (const float*)d_in[10];
    const float* thf = (const float*)d_in[11];
    const float* thi = (const float*)d_in[12];
    const float* thu = (const float*)d_in[13];
    const float* tho = (const float*)d_in[14];

    float* Wp  = (float*)d_ws;            // 260*16 floats = 16640 B
    float* bth = Wp + FANIN * 16;         // 16 floats

    qlstm_prep<<<(FANIN * 16 + 255) / 256, 256, 0, stream>>>(
        Wf, bf, Wi, bi, Wu, bu, Wo, bo, thf, thi, thu, tho, Wp, bth);

    qlstm_main<<<NB / 64, TPB, 0, stream>>>(
        x, hx, cx, Wp, bth, (float*)d_out);
}